// Round 1
// baseline (58208.502 us; speedup 1.0000x reference)
//
#include <hip/hip_runtime.h>
#include <math.h>

// ---------------- problem constants ----------------
constexpr int Bz = 16;
constexpr int Sz = 512;
constexpr int Dz = 512;
constexpr int T1 = Sz + 1;     // 513
constexpr int UPS = 3;
constexpr int TU = Sz * UPS;   // 1536
constexpr int G4 = 4 * Dz;     // 2048
constexpr float THRESHc = 1.0f;
constexpr float SM1c = 1.0f, NT1c = 0.0f;
constexpr float TAILc = 0.45f;
constexpr float SM2c = 0.25f, NT2c = 0.01f;

// LSTM persistent-kernel geometry
constexpr int NSL = 128;       // slices per direction (4 h-dims each)
constexpr int NROW = 16;       // gate rows per WG (4 h-dims x 4 gates)
constexpr int PADW = 516;      // padded LDS row stride (floats), 16B aligned

// output layout (floats)
constexpr int EMB_OFF = 0;
constexpr int TOK_OFF = Bz * T1 * Dz;            // 4202496
constexpr int ALUT_OFF = TOK_OFF + Bz;           // 4202512
constexpr int USA_OFF = ALUT_OFF + Bz * T1;      // 4210720
constexpr int USP_OFF = USA_OFF + Bz * TU;       // 4235296

__device__ __forceinline__ float sigm(float x) { return 1.0f / (1.0f + expf(-x)); }

// ---------------- K0a: transpose conv_w -> wt[(i*3+k)*512 + d] ----------------
__global__ void k_transpose_convw(const float* __restrict__ cw, float* __restrict__ wt) {
    __shared__ float tile[64][65];
    int dt = blockIdx.x * 64, ct = blockIdx.y * 64;
    int tx = threadIdx.x & 63, ty = threadIdx.x >> 6;
    for (int r = ty; r < 64; r += 4)
        tile[r][tx] = cw[(dt + r) * 1536 + ct + tx];
    __syncthreads();
    for (int r = ty; r < 64; r += 4)
        wt[(ct + r) * 512 + dt + tx] = tile[tx][r];
}

// ---------------- K0b: transpose up_w -> upt[(k*512+o)*512 + i] ----------------
__global__ void k_transpose_upw(const float* __restrict__ uw, float* __restrict__ upt) {
    __shared__ float tile[64][65];
    int it = blockIdx.x * 64, ct = blockIdx.y * 64;
    int tx = threadIdx.x & 63, ty = threadIdx.x >> 6;
    for (int r = ty; r < 64; r += 4)
        tile[r][tx] = uw[(it + r) * 1536 + ct + tx];
    __syncthreads();
    for (int r = ty; r < 64; r += 4) {
        int c = ct + r;
        int k = c % 3, o = c / 3;
        upt[(k * 512 + o) * 512 + it + tx] = tile[tx][r];
    }
}

// ---------------- K0c: gconst[dir*2048+g] = b_ih+b_hh+sum_o up_b[o]*w_ih[g][o] ----------------
__global__ void k_gconst(const float* __restrict__ wih_f, const float* __restrict__ bih_f,
                         const float* __restrict__ bhh_f, const float* __restrict__ wih_b,
                         const float* __restrict__ bih_b, const float* __restrict__ bhh_b,
                         const float* __restrict__ upb, float* __restrict__ gconst) {
    int g = blockIdx.x * 256 + threadIdx.x;   // 0..4095
    int dir = g >> 11, gg = g & 2047;
    const float* wih = dir ? wih_b : wih_f;
    const float* bi = dir ? bih_b : bih_f;
    const float* bh = dir ? bhh_b : bhh_f;
    float s = bi[gg] + bh[gg];
    const float4* w4 = (const float4*)(wih + (size_t)gg * 512);
    const float4* u4 = (const float4*)upb;
    for (int o = 0; o < 128; ++o) {
        float4 w = w4[o], u = u4[o];
        s += w.x * u.x + w.y * u.y + w.z * u.z + w.w * u.w;
    }
    gconst[g] = s;
}

// ---------------- K1: M[(dir*3+k)*2048+g][i] = sum_o w_ih[g][o] * upt[k][o][i] ----------------
__global__ void k_gemm_M(const float* __restrict__ wih_f, const float* __restrict__ wih_b,
                         const float* __restrict__ upt, float* __restrict__ Mout) {
    __shared__ float As[32][68];
    __shared__ float Bs[32][68];
    int z = blockIdx.z;
    int dir = z / 3, k = z % 3;
    const float* A = dir ? wih_b : wih_f;
    const float* Bt = upt + (size_t)k * 512 * 512;
    int g0 = blockIdx.y * 64, i0 = blockIdx.x * 64;
    int tid = threadIdx.x;
    int tx = tid & 15, ty = tid >> 4;
    float acc[4][4] = {};
    for (int k0 = 0; k0 < 512; k0 += 32) {
#pragma unroll
        for (int e = 0; e < 8; ++e) {
            int idx = e * 256 + tid;
            int ko = idx & 31, gl = idx >> 5;
            As[ko][gl] = A[(size_t)(g0 + gl) * 512 + k0 + ko];
        }
#pragma unroll
        for (int e = 0; e < 8; ++e) {
            int idx = e * 256 + tid;
            int il = idx & 63, ko = idx >> 6;
            Bs[ko][il] = Bt[(size_t)(k0 + ko) * 512 + i0 + il];
        }
        __syncthreads();
#pragma unroll
        for (int ko = 0; ko < 32; ++ko) {
            float4 a = *(const float4*)&As[ko][ty * 4];
            float4 b = *(const float4*)&Bs[ko][tx * 4];
            acc[0][0] += a.x * b.x; acc[0][1] += a.x * b.y; acc[0][2] += a.x * b.z; acc[0][3] += a.x * b.w;
            acc[1][0] += a.y * b.x; acc[1][1] += a.y * b.y; acc[1][2] += a.y * b.z; acc[1][3] += a.y * b.w;
            acc[2][0] += a.z * b.x; acc[2][1] += a.z * b.y; acc[2][2] += a.z * b.z; acc[2][3] += a.z * b.w;
            acc[3][0] += a.w * b.x; acc[3][1] += a.w * b.y; acc[3][2] += a.w * b.z; acc[3][3] += a.w * b.w;
        }
        __syncthreads();
    }
#pragma unroll
    for (int r = 0; r < 4; ++r) {
        float4 o = make_float4(acc[r][0], acc[r][1], acc[r][2], acc[r][3]);
        *(float4*)&Mout[(size_t)(z * 2048 + g0 + ty * 4 + r) * 512 + i0 + tx * 4] = o;
    }
}

// ---------------- K2: conv1d(pad1,k3)+relu then dot(out_w)+sigmoid -> alphas_s[b][s] ----------------
__global__ void k_conv_alpha(const float* __restrict__ hidden, const float* __restrict__ wt,
                             const float* __restrict__ cb, const float* __restrict__ ow,
                             const float* __restrict__ ob, const float* __restrict__ mask,
                             float* __restrict__ alph_s) {
    __shared__ float hs[18 * 512];
    __shared__ float red[16][257];
    int b = blockIdx.x, s0 = blockIdx.y * 16;
    int tid = threadIdx.x;
#pragma unroll
    for (int e = 0; e < 36; ++e) {
        int idx = e * 256 + tid;
        int r = idx >> 9, i = idx & 511;
        int s = s0 + r - 1;
        hs[idx] = (s >= 0 && s < Sz) ? hidden[((size_t)b * Sz + s) * Dz + i] : 0.f;
    }
    __syncthreads();
    float acc0[16] = {}, acc1[16] = {};
    int d0 = tid, d1 = tid + 256;
    for (int i = 0; i < 512; ++i) {
        float w00 = wt[(i * 3 + 0) * 512 + d0];
        float w01 = wt[(i * 3 + 1) * 512 + d0];
        float w02 = wt[(i * 3 + 2) * 512 + d0];
        float w10 = wt[(i * 3 + 0) * 512 + d1];
        float w11 = wt[(i * 3 + 1) * 512 + d1];
        float w12 = wt[(i * 3 + 2) * 512 + d1];
        float hv[18];
#pragma unroll
        for (int r = 0; r < 18; ++r) hv[r] = hs[r * 512 + i];
#pragma unroll
        for (int j = 0; j < 16; ++j) {
            acc0[j] += hv[j] * w00 + hv[j + 1] * w01 + hv[j + 2] * w02;
            acc1[j] += hv[j] * w10 + hv[j + 1] * w11 + hv[j + 2] * w12;
        }
    }
    float cb0 = cb[d0], cb1 = cb[d1], ow0 = ow[d0], ow1 = ow[d1];
#pragma unroll
    for (int j = 0; j < 16; ++j)
        red[j][tid] = fmaxf(acc0[j] + cb0, 0.f) * ow0 + fmaxf(acc1[j] + cb1, 0.f) * ow1;
    __syncthreads();
    for (int off = 128; off >= 1; off >>= 1) {
        if (tid < off) {
#pragma unroll
            for (int j = 0; j < 16; ++j) red[j][tid] += red[j][tid + off];
        }
        __syncthreads();
    }
    if (tid < 16) {
        float v = red[tid][0] + ob[0];
        float a = sigm(v);
        a = fmaxf(a * SM1c - NT1c, 0.f);
        a *= mask[b * Sz + s0 + tid];
        alph_s[b * Sz + s0 + tid] = a;
    }
}

// ---------------- K3: CIF scalar scan (serial per batch) ----------------
__global__ void k_cif_scan(const float* __restrict__ alph_s, const float* __restrict__ mask,
                           float* __restrict__ out, float* __restrict__ sc_cur,
                           float* __restrict__ sc_res, int* __restrict__ sc_dst) {
    __shared__ float sa[16][T1];
    int tid = threadIdx.x;
    for (int idx = tid; idx < 16 * T1; idx += 256) {
        int b = idx / T1, t = idx % T1;
        float a = (t < Sz) ? alph_s[b * Sz + t] : 0.f;
        float mp = (t == 0) ? 1.f : mask[b * Sz + t - 1];
        float mc = (t < Sz) ? mask[b * Sz + t] : 0.f;
        sa[b][t] = a + (mp - mc) * TAILc;
    }
    __syncthreads();
    if (tid < 16) {
        int b = tid;
        float integ = 0.f, sum = 0.f;
        int nf = 0;
        for (int t = 0; t < T1; ++t) {
            float a = sa[b][t];
            out[ALUT_OFF + b * T1 + t] = a;
            sum += a;
            float dist = 1.f - integ;
            integ += a;
            bool fire = (integ >= THRESHc);
            float cur = fire ? dist : a;
            sc_cur[b * T1 + t] = cur;
            sc_res[b * T1 + t] = fire ? (a - cur) : 0.f;
            sc_dst[b * T1 + t] = fire ? (nf++) : -1;
            if (fire) integ -= 1.f;
        }
        out[TOK_OFF + b] = floorf(sum);
    }
}

// ---------------- K4: CIF frame accumulation / scatter ----------------
__global__ void k_cif_frames(const float* __restrict__ hidden, const float* __restrict__ sc_cur,
                             const float* __restrict__ sc_res, const int* __restrict__ sc_dst,
                             float* __restrict__ out) {
    __shared__ float cu[T1], re[T1];
    __shared__ int dsx[T1];
    int b = blockIdx.x, d = blockIdx.y * 256 + threadIdx.x;
    for (int t = threadIdx.x; t < T1; t += 256) {
        cu[t] = sc_cur[b * T1 + t];
        re[t] = sc_res[b * T1 + t];
        dsx[t] = sc_dst[b * T1 + t];
    }
    __syncthreads();
    float frame = 0.f;
    for (int t = 0; t < T1; ++t) {
        float ht = (t < Sz) ? hidden[((size_t)b * Sz + t) * Dz + d] : 0.f;
        float f = frame + cu[t] * ht;
        int dst = dsx[t];
        if (dst >= 0) {
            out[EMB_OFF + ((size_t)b * T1 + dst) * Dz + d] = f;
            frame = re[t] * ht;
        } else {
            frame = f;
        }
    }
}

// ---------------- K5: persistent cooperative BiLSTM ----------------
__global__ void __launch_bounds__(256, 1)
k_lstm(const float* __restrict__ hidden, const float* __restrict__ Mw,
       const float* __restrict__ gconst, const float* __restrict__ whh_f,
       const float* __restrict__ whh_b, const float* __restrict__ w2,
       float* __restrict__ h_buf, float* __restrict__ part, int* __restrict__ flags) {
    extern __shared__ float lds[];
    float* gbuf = lds + 4 * NROW * PADW;   // 256 floats
    int wg = blockIdx.x;                   // 0..255
    int dir = wg >> 7;
    int slice = wg & 127;
    int d0 = slice * 4;
    int tid = threadIdx.x;
    const float* whh = dir ? whh_b : whh_f;

    // stage weights: mats 0..2 = M_k, mat 3 = w_hh ; row j = q*4+dd -> gate q*512+d0+dd
    for (int e = 0; e < 128; ++e) {
        int idx = e * 256 + tid;          // 0..32767
        int i = idx & 511;
        int row = (idx >> 9) & 15;
        int mat = idx >> 13;
        int q = row >> 2, dd = row & 3;
        int gr = q * 512 + d0 + dd;
        float v;
        if (mat < 3) v = Mw[((size_t)(dir * 3 + mat) * 2048 + gr) * 512 + i];
        else v = whh[(size_t)gr * 512 + i];
        lds[(mat * NROW + row) * PADW + i] = v;
    }

    int r = tid >> 4, bb = tid & 15;               // dot-phase mapping
    int qr = r >> 2, ddr = r & 3;
    float gc = gconst[dir * 2048 + qr * 512 + d0 + ddr];
    int dds = tid & 3, bs = tid >> 2;              // gate-phase mapping (tid<64)
    float w2v = (tid < 64) ? w2[dir * 512 + d0 + dds] : 0.f;
    float cstate = 0.f;
    float* hb0 = h_buf + (size_t)dir * 2 * Bz * Dz;
    int* myflags = flags + dir * TU;
    __syncthreads();

    for (int n = 0; n < TU; ++n) {
        int t = dir ? (TU - 1 - n) : n;
        int s = t / 3, k = t % 3;
        if (n > 0) {
            if (tid == 0) {
                int guard = 0;
                while (__hip_atomic_load(&myflags[n - 1], __ATOMIC_RELAXED,
                                         __HIP_MEMORY_SCOPE_AGENT) != NSL &&
                       guard < (1 << 24)) {
                    __builtin_amdgcn_s_sleep(1);
                    ++guard;
                }
                (void)__hip_atomic_load(&myflags[n - 1], __ATOMIC_ACQUIRE,
                                        __HIP_MEMORY_SCOPE_AGENT);
            }
            __syncthreads();
        }
        const float4* mk4 = (const float4*)(lds + (k * NROW + r) * PADW);
        const float4* wh4 = (const float4*)(lds + (3 * NROW + r) * PADW);
        const float4* hid4 = (const float4*)(hidden + ((size_t)bb * Sz + s) * Dz);
        const float4* hp4 = (const float4*)(hb0 + (size_t)((n - 1) & 1) * Bz * Dz + (size_t)bb * Dz);
        float a0 = 0.f, a1 = 0.f, a2 = 0.f, a3 = 0.f;
        if (n > 0) {
#pragma unroll 4
            for (int i4 = 0; i4 < 128; ++i4) {
                float4 mw = mk4[i4], xv = hid4[i4];
                float4 ww = wh4[i4], hv = hp4[i4];
                a0 += mw.x * xv.x + ww.x * hv.x;
                a1 += mw.y * xv.y + ww.y * hv.y;
                a2 += mw.z * xv.z + ww.z * hv.z;
                a3 += mw.w * xv.w + ww.w * hv.w;
            }
        } else {
#pragma unroll 4
            for (int i4 = 0; i4 < 128; ++i4) {
                float4 mw = mk4[i4], xv = hid4[i4];
                a0 += mw.x * xv.x;
                a1 += mw.y * xv.y;
                a2 += mw.z * xv.z;
                a3 += mw.w * xv.w;
            }
        }
        gbuf[r * 16 + bb] = gc + ((a0 + a1) + (a2 + a3));
        __syncthreads();
        if (tid < 64) {
            float gi = gbuf[(0 * 4 + dds) * 16 + bs];
            float gf = gbuf[(1 * 4 + dds) * 16 + bs];
            float gg = gbuf[(2 * 4 + dds) * 16 + bs];
            float go = gbuf[(3 * 4 + dds) * 16 + bs];
            float si = sigm(gi), sf = sigm(gf), so = sigm(go);
            float tg = tanhf(gg);
            cstate = sf * cstate + si * tg;
            float h = so * tanhf(cstate);
            hb0[(size_t)(n & 1) * Bz * Dz + (size_t)bs * Dz + d0 + dds] = h;
            float p = h * w2v;
            p += __shfl_xor(p, 1);
            p += __shfl_xor(p, 2);
            if (dds == 0)
                part[((size_t)(dir * NSL + slice) * Bz + bs) * TU + t] = p;
        }
        __syncthreads();
        if (tid == 0) {
            __threadfence();
            atomicAdd(&myflags[n], 1);
        }
    }
}

// ---------------- K6: reduce us partials, activation, pre-norm ----------------
__global__ void k_us_reduce(const float* __restrict__ part, const float* __restrict__ ob2,
                            const float* __restrict__ mask, float* __restrict__ usA,
                            float* __restrict__ csum) {
    int b = blockIdx.x, ch = blockIdx.y;
    int t = ch * 256 + threadIdx.x;
    float s = 0.f;
#pragma unroll 8
    for (int p = 0; p < 256; ++p) s += part[((size_t)p * Bz + b) * TU + t];
    float u = sigm(s + ob2[0]);
    float ua = fmaxf(u * SM2c - NT2c, 0.f) * mask[b * Sz + t / 3];
    usA[b * TU + t] = ua;
    __shared__ float red[256];
    red[threadIdx.x] = ua;
    __syncthreads();
    for (int off = 128; off >= 1; off >>= 1) {
        if (threadIdx.x < off) red[threadIdx.x] += red[threadIdx.x + off];
        __syncthreads();
    }
    if (threadIdx.x == 0) csum[b * 6 + ch] = red[0];
}

// ---------------- K7: normalize + peak scan (serial per batch) ----------------
__global__ void k_us_scan(const float* __restrict__ usA, const float* __restrict__ csum,
                          float* __restrict__ out) {
    __shared__ float ubuf[TU];
    int b = blockIdx.x;
    for (int t = threadIdx.x; t < TU; t += 64) ubuf[t] = usA[b * TU + t];
    __syncthreads();
    if (threadIdx.x == 0) {
        float tot = 0.f;
        for (int c = 0; c < 6; ++c) tot += csum[b * 6 + c];
        float scale = out[TOK_OFF + b] / tot;
        float integ = 0.f;
        const float th = THRESHc - 0.0001f;
        for (int t = 0; t < TU; ++t) {
            float ua = ubuf[t] * scale;
            out[USA_OFF + b * TU + t] = ua;
            integ += ua;
            out[USP_OFF + b * TU + t] = integ;
            if (integ >= th) integ -= th;
        }
    }
}

// ---------------- host ----------------
extern "C" void kernel_launch(void* const* d_in, const int* in_sizes, int n_in,
                              void* d_out, int out_size, void* d_ws, size_t ws_size,
                              hipStream_t stream) {
    const float* hidden = (const float*)d_in[0];
    const float* mask   = (const float*)d_in[1];
    const float* conv_w = (const float*)d_in[2];
    const float* conv_b = (const float*)d_in[3];
    const float* out_w  = (const float*)d_in[4];
    const float* out_b  = (const float*)d_in[5];
    const float* up_w   = (const float*)d_in[6];
    const float* up_b   = (const float*)d_in[7];
    const float* w_ih_f = (const float*)d_in[8];
    const float* w_hh_f = (const float*)d_in[9];
    const float* b_ih_f = (const float*)d_in[10];
    const float* b_hh_f = (const float*)d_in[11];
    const float* w_ih_b = (const float*)d_in[12];
    const float* w_hh_b = (const float*)d_in[13];
    const float* b_ih_b = (const float*)d_in[14];
    const float* b_hh_b = (const float*)d_in[15];
    const float* out2_w = (const float*)d_in[16];
    const float* out2_b = (const float*)d_in[17];
    float* out = (float*)d_out;
    float* ws = (float*)d_ws;

    // workspace layout (floats)
    float* wt     = ws + 0;          // 786432
    float* upt    = ws + 786432;     // 786432
    float* Mw     = ws + 1572864;    // 6291456
    float* gconst = ws + 7864320;    // 4096
    float* alph_s = ws + 7868416;    // 8192
    float* sc_cur = ws + 7876608;    // 8208
    float* sc_res = ws + 7884816;    // 8208
    int*   sc_dst = (int*)(ws + 7893024);   // 8208
    float* h_buf  = ws + 7901232;    // 32768
    float* part   = ws + 7934000;    // 6291456
    float* usA    = ws + 14225456;   // 24576
    float* csum   = ws + 14250032;   // 96
    int*   flags  = (int*)(ws + 14250128);  // 3072 ints

    hipMemsetAsync(out, 0, (size_t)Bz * T1 * Dz * sizeof(float), stream);   // embeds region
    hipMemsetAsync(flags, 0, 2 * TU * sizeof(int), stream);

    k_transpose_convw<<<dim3(8, 24), 256, 0, stream>>>(conv_w, wt);
    k_transpose_upw<<<dim3(8, 24), 256, 0, stream>>>(up_w, upt);
    k_gconst<<<16, 256, 0, stream>>>(w_ih_f, b_ih_f, b_hh_f, w_ih_b, b_ih_b, b_hh_b, up_b, gconst);
    k_gemm_M<<<dim3(8, 32, 6), 256, 0, stream>>>(w_ih_f, w_ih_b, upt, Mw);
    k_conv_alpha<<<dim3(16, 32), 256, 0, stream>>>(hidden, wt, conv_b, out_w, out_b, mask, alph_s);
    k_cif_scan<<<1, 256, 0, stream>>>(alph_s, mask, out, sc_cur, sc_res, sc_dst);
    k_cif_frames<<<dim3(16, 2), 256, 0, stream>>>(hidden, sc_cur, sc_res, sc_dst, out);

    {
        size_t shmem = (size_t)(4 * NROW * PADW + 256) * sizeof(float);  // 133120 B
        hipFuncSetAttribute(reinterpret_cast<const void*>(&k_lstm),
                            hipFuncAttributeMaxDynamicSharedMemorySize, (int)(shmem + 1024));
        void* args[] = { (void*)&hidden, (void*)&Mw, (void*)&gconst, (void*)&w_hh_f,
                         (void*)&w_hh_b, (void*)&out2_w, (void*)&h_buf, (void*)&part,
                         (void*)&flags };
        hipLaunchCooperativeKernel(reinterpret_cast<void*>(&k_lstm), dim3(256), dim3(256),
                                   args, (unsigned)shmem, stream);
    }

    k_us_reduce<<<dim3(16, 6), 256, 0, stream>>>(part, out2_b, mask, usA, csum);
    k_us_scan<<<16, 64, 0, stream>>>(usA, csum, out);
}

// Round 3
// 14640.889 us; speedup vs baseline: 3.9757x; 3.9757x over previous
//
#include <hip/hip_runtime.h>
#include <math.h>

// ---------------- problem constants ----------------
constexpr int Bz = 16;
constexpr int Sz = 512;
constexpr int Dz = 512;
constexpr int T1 = Sz + 1;     // 513
constexpr int TU = Sz * 3;     // 1536
constexpr float THRESHc = 1.0f;
constexpr float SM1c = 1.0f, NT1c = 0.0f;
constexpr float TAILc = 0.45f;
constexpr float SM2c = 0.25f, NT2c = 0.01f;

// LSTM persistent-kernel geometry
constexpr int NWG_DIR = 32;    // WGs per direction (grid 64)
constexpr int GD = 16;         // h-dims per WG
constexpr int PADsh = 520;     // LDS row stride (bf16 elems): 1040 B = 4 banks mod 32 -> 2-way max

// output layout (floats)
constexpr int EMB_OFF = 0;
constexpr int TOK_OFF = Bz * T1 * Dz;            // 4202496
constexpr int ALUT_OFF = TOK_OFF + Bz;           // 4202512
constexpr int USA_OFF = ALUT_OFF + Bz * T1;      // 4210720
constexpr int USP_OFF = USA_OFF + Bz * TU;       // 4235296

typedef short bf16x8 __attribute__((ext_vector_type(8)));
typedef float f32x4 __attribute__((ext_vector_type(4)));
typedef unsigned long long u64;

__device__ __forceinline__ float sigm(float x) { return 1.0f / (1.0f + expf(-x)); }
__device__ __forceinline__ unsigned short f2bf(float f) {
    unsigned u = __float_as_uint(f);
    return (unsigned short)((u + 0x7fffu + ((u >> 16) & 1u)) >> 16);
}
__device__ __forceinline__ float bf2f(unsigned short u) {
    return __uint_as_float(((unsigned)u) << 16);
}
__device__ __forceinline__ void splitf(float x, unsigned short& hi, unsigned short& lo) {
    unsigned short h = f2bf(x);
    hi = h;
    lo = f2bf(x - bf2f(h));
}

// coherent (MALL) flag load — explicit sc0 sc1, no codegen ambiguity
__device__ __forceinline__ int flag_load(const int* p) {
    int v;
    asm volatile("global_load_dword %0, %1, off sc0 sc1\n\ts_waitcnt vmcnt(0)"
                 : "=v"(v) : "v"(p));
    return v;
}

// ---------------- K0a: transpose conv_w -> wt[(i*3+k)*512 + d] ----------------
__global__ void k_transpose_convw(const float* __restrict__ cw, float* __restrict__ wt) {
    __shared__ float tile[64][65];
    int dt = blockIdx.x * 64, ct = blockIdx.y * 64;
    int tx = threadIdx.x & 63, ty = threadIdx.x >> 6;
    for (int r = ty; r < 64; r += 4)
        tile[r][tx] = cw[(dt + r) * 1536 + ct + tx];
    __syncthreads();
    for (int r = ty; r < 64; r += 4)
        wt[(ct + r) * 512 + dt + tx] = tile[tx][r];
}

// ---------------- K0c: gconst[dir*2048+g] = b_ih+b_hh+sum_o up_b[o]*w_ih[g][o] ----------------
__global__ void k_gconst(const float* __restrict__ wih_f, const float* __restrict__ bih_f,
                         const float* __restrict__ bhh_f, const float* __restrict__ wih_b,
                         const float* __restrict__ bih_b, const float* __restrict__ bhh_b,
                         const float* __restrict__ upb, float* __restrict__ gconst) {
    int g = blockIdx.x * 256 + threadIdx.x;   // 0..4095
    int dir = g >> 11, gg = g & 2047;
    const float* wih = dir ? wih_b : wih_f;
    const float* bi = dir ? bih_b : bih_f;
    const float* bh = dir ? bhh_b : bhh_f;
    float s = bi[gg] + bh[gg];
    const float4* w4 = (const float4*)(wih + (size_t)gg * 512);
    const float4* u4 = (const float4*)upb;
    for (int o = 0; o < 128; ++o) {
        float4 w = w4[o], u = u4[o];
        s += w.x * u.x + w.y * u.y + w.z * u.z + w.w * u.w;
    }
    gconst[g] = s;
}

// ---------------- K1: U[k][b*512+s][o] = sum_i hidden[b,s,i]*up_w[i,o,k], split bf16 ----------------
__global__ void k_U(const float* __restrict__ hidden, const float* __restrict__ up_w,
                    unsigned short* __restrict__ Uhi, unsigned short* __restrict__ Ulo) {
    __shared__ float As[32][68];   // [i-local][bs-local]
    __shared__ float Bs[32][68];   // [i-local][o-local]
    int k = blockIdx.z;
    int bs0 = blockIdx.y * 64, o0 = blockIdx.x * 64;
    int tid = threadIdx.x;
    int tx = tid & 15, ty = tid >> 4;
    float acc[4][4] = {};
    for (int k0 = 0; k0 < 512; k0 += 32) {
#pragma unroll
        for (int e = 0; e < 8; ++e) {
            int idx = e * 256 + tid;
            int c = idx & 31, rr = idx >> 5;
            As[c][rr] = hidden[(size_t)(bs0 + rr) * 512 + k0 + c];
        }
#pragma unroll
        for (int e = 0; e < 8; ++e) {
            int idx = e * 256 + tid;
            int rr = idx & 63, c = idx >> 6;   // lanes -> consecutive o (stride 3 floats)
            Bs[c][rr] = up_w[(size_t)(k0 + c) * 1536 + (o0 + rr) * 3 + k];
        }
        __syncthreads();
#pragma unroll
        for (int ko = 0; ko < 32; ++ko) {
            float4 a = *(const float4*)&As[ko][ty * 4];
            float4 b = *(const float4*)&Bs[ko][tx * 4];
            acc[0][0] += a.x * b.x; acc[0][1] += a.x * b.y; acc[0][2] += a.x * b.z; acc[0][3] += a.x * b.w;
            acc[1][0] += a.y * b.x; acc[1][1] += a.y * b.y; acc[1][2] += a.y * b.z; acc[1][3] += a.y * b.w;
            acc[2][0] += a.z * b.x; acc[2][1] += a.z * b.y; acc[2][2] += a.z * b.z; acc[2][3] += a.z * b.w;
            acc[3][0] += a.w * b.x; acc[3][1] += a.w * b.y; acc[3][2] += a.w * b.z; acc[3][3] += a.w * b.w;
        }
        __syncthreads();
    }
#pragma unroll
    for (int r = 0; r < 4; ++r) {
        ushort4 wh, wl;
        splitf(acc[r][0], wh.x, wl.x); splitf(acc[r][1], wh.y, wl.y);
        splitf(acc[r][2], wh.z, wl.z); splitf(acc[r][3], wh.w, wl.w);
        size_t off = ((size_t)(k * 8192 + bs0 + ty * 4 + r)) * 512 + o0 + tx * 4;
        *(ushort4*)&Uhi[off] = wh;
        *(ushort4*)&Ulo[off] = wl;
    }
}

// ---------------- K2: conv1d(pad1,k3)+relu then dot(out_w)+sigmoid -> alphas_s[b][s] ----------------
__global__ void k_conv_alpha(const float* __restrict__ hidden, const float* __restrict__ wt,
                             const float* __restrict__ cb, const float* __restrict__ ow,
                             const float* __restrict__ ob, const float* __restrict__ mask,
                             float* __restrict__ alph_s) {
    __shared__ float hs[18 * 512];
    __shared__ float red[16][257];
    int b = blockIdx.x, s0 = blockIdx.y * 16;
    int tid = threadIdx.x;
#pragma unroll
    for (int e = 0; e < 36; ++e) {
        int idx = e * 256 + tid;
        int r = idx >> 9, i = idx & 511;
        int s = s0 + r - 1;
        hs[idx] = (s >= 0 && s < Sz) ? hidden[((size_t)b * Sz + s) * Dz + i] : 0.f;
    }
    __syncthreads();
    float acc0[16] = {}, acc1[16] = {};
    int d0 = tid, d1 = tid + 256;
    for (int i = 0; i < 512; ++i) {
        float w00 = wt[(i * 3 + 0) * 512 + d0];
        float w01 = wt[(i * 3 + 1) * 512 + d0];
        float w02 = wt[(i * 3 + 2) * 512 + d0];
        float w10 = wt[(i * 3 + 0) * 512 + d1];
        float w11 = wt[(i * 3 + 1) * 512 + d1];
        float w12 = wt[(i * 3 + 2) * 512 + d1];
        float hv[18];
#pragma unroll
        for (int r = 0; r < 18; ++r) hv[r] = hs[r * 512 + i];
#pragma unroll
        for (int j = 0; j < 16; ++j) {
            acc0[j] += hv[j] * w00 + hv[j + 1] * w01 + hv[j + 2] * w02;
            acc1[j] += hv[j] * w10 + hv[j + 1] * w11 + hv[j + 2] * w12;
        }
    }
    float cb0 = cb[d0], cb1 = cb[d1], ow0 = ow[d0], ow1 = ow[d1];
#pragma unroll
    for (int j = 0; j < 16; ++j)
        red[j][tid] = fmaxf(acc0[j] + cb0, 0.f) * ow0 + fmaxf(acc1[j] + cb1, 0.f) * ow1;
    __syncthreads();
    for (int off = 128; off >= 1; off >>= 1) {
        if (tid < off) {
#pragma unroll
            for (int j = 0; j < 16; ++j) red[j][tid] += red[j][tid + off];
        }
        __syncthreads();
    }
    if (tid < 16) {
        float v = red[tid][0] + ob[0];
        float a = sigm(v);
        a = fmaxf(a * SM1c - NT1c, 0.f);
        a *= mask[b * Sz + s0 + tid];
        alph_s[b * Sz + s0 + tid] = a;
    }
}

// ---------------- K3: CIF scalar scan (serial per batch) ----------------
__global__ void k_cif_scan(const float* __restrict__ alph_s, const float* __restrict__ mask,
                           float* __restrict__ out, float* __restrict__ sc_cur,
                           float* __restrict__ sc_res, int* __restrict__ sc_dst) {
    __shared__ float sa[16][T1];
    int tid = threadIdx.x;
    for (int idx = tid; idx < 16 * T1; idx += 256) {
        int b = idx / T1, t = idx % T1;
        float a = (t < Sz) ? alph_s[b * Sz + t] : 0.f;
        float mp = (t == 0) ? 1.f : mask[b * Sz + t - 1];
        float mc = (t < Sz) ? mask[b * Sz + t] : 0.f;
        sa[b][t] = a + (mp - mc) * TAILc;
    }
    __syncthreads();
    if (tid < 16) {
        int b = tid;
        float integ = 0.f, sum = 0.f;
        int nf = 0;
        for (int t = 0; t < T1; ++t) {
            float a = sa[b][t];
            out[ALUT_OFF + b * T1 + t] = a;
            sum += a;
            float dist = 1.f - integ;
            integ += a;
            bool fire = (integ >= THRESHc);
            float cur = fire ? dist : a;
            sc_cur[b * T1 + t] = cur;
            sc_res[b * T1 + t] = fire ? (a - cur) : 0.f;
            sc_dst[b * T1 + t] = fire ? (nf++) : -1;
            if (fire) integ -= 1.f;
        }
        out[TOK_OFF + b] = floorf(sum);
    }
}

// ---------------- K4: CIF frame accumulation / scatter ----------------
__global__ void k_cif_frames(const float* __restrict__ hidden, const float* __restrict__ sc_cur,
                             const float* __restrict__ sc_res, const int* __restrict__ sc_dst,
                             float* __restrict__ out) {
    __shared__ float cu[T1], re[T1];
    __shared__ int dsx[T1];
    int b = blockIdx.x, d = blockIdx.y * 256 + threadIdx.x;
    for (int t = threadIdx.x; t < T1; t += 256) {
        cu[t] = sc_cur[b * T1 + t];
        re[t] = sc_res[b * T1 + t];
        dsx[t] = sc_dst[b * T1 + t];
    }
    __syncthreads();
    float frame = 0.f;
    for (int t = 0; t < T1; ++t) {
        float ht = (t < Sz) ? hidden[((size_t)b * Sz + t) * Dz + d] : 0.f;
        float f = frame + cu[t] * ht;
        int dst = dsx[t];
        if (dst >= 0) {
            out[EMB_OFF + ((size_t)b * T1 + dst) * Dz + d] = f;
            frame = re[t] * ht;
        } else {
            frame = f;
        }
    }
}

// ---------------- K5: persistent cooperative BiLSTM (split-bf16 MFMA, explicit sc0/sc1 exchange) ----
__global__ void __launch_bounds__(256, 1)
k_lstm(const float* __restrict__ wih_f, const float* __restrict__ whh_f,
       const float* __restrict__ wih_b, const float* __restrict__ whh_b,
       const float* __restrict__ gconst, const float* __restrict__ w2,
       const unsigned short* __restrict__ Uhi, const unsigned short* __restrict__ Ulo,
       unsigned short* hHi, unsigned short* hLo, float* part, int* flags) {
    extern __shared__ unsigned short lds[];
    unsigned short* HHhi = lds;                       // [64][520] bf16
    unsigned short* HHlo = lds + 64 * PADsh;          // [64][520] bf16
    float* xch = (float*)(lds + 2 * 64 * PADsh);      // [3][16][16] f32

    const int wg = blockIdx.x;                        // 0..63
    const int dir = wg >> 5, slice = wg & 31;
    const int d0 = slice * GD;
    const int tid = threadIdx.x;
    const int wv = tid >> 6;                          // wave = gate (0:i 1:f 2:g 3:o)
    const int l = tid & 63;
    const int colb = l & 15;                          // batch col / weight-row-in-tile
    const int khi = l >> 4;
    const float* wih = dir ? wih_b : wih_f;
    const float* whh = dir ? whh_b : whh_f;

    // stage split w_hh into LDS: row r = q*16+dd -> gate row q*512 + d0 + dd
    for (int idx = tid; idx < 64 * 128; idx += 256) {
        int row = idx >> 7, c4 = (idx & 127) << 2;
        int grow = (row >> 4) * 512 + d0 + (row & 15);
        float4 w4 = *(const float4*)&whh[(size_t)grow * 512 + c4];
        ushort4 h4, l4;
        splitf(w4.x, h4.x, l4.x); splitf(w4.y, h4.y, l4.y);
        splitf(w4.z, h4.z, l4.z); splitf(w4.w, h4.w, l4.w);
        *(ushort4*)&HHhi[row * PADsh + c4] = h4;
        *(ushort4*)&HHlo[row * PADsh + c4] = l4;
    }

    f32x4 bias;
    float w2v[4], cst[4] = {0.f, 0.f, 0.f, 0.f};
#pragma unroll
    for (int j = 0; j < 4; ++j) {
        bias[j] = gconst[dir * 2048 + wv * 512 + d0 + khi * 4 + j];
        w2v[j] = w2[dir * 512 + d0 + khi * 4 + j];
    }
    const float* wihrow = wih + (size_t)(wv * 512 + d0 + colb) * 512 + khi * 8;
    int* myflag = flags + dir * TU;
    __syncthreads();

    for (int n = 0; n < TU; ++n) {
        int t = dir ? (TU - 1 - n) : n;
        int s = t / 3, k = t - 3 * s;

        // ---- pre-poll: U-dot (independent of h) ----
        f32x4 acc = bias;
        {
            const unsigned short* ub = Uhi + ((size_t)(k * 8192 + colb * 512 + s)) * 512 + khi * 8;
            const unsigned short* ul = Ulo + ((size_t)(k * 8192 + colb * 512 + s)) * 512 + khi * 8;
#pragma unroll
            for (int m = 0; m < 16; ++m) {
                float4 wa = *(const float4*)(wihrow + m * 32);
                float4 wb = *(const float4*)(wihrow + m * 32 + 4);
                union { unsigned short u[8]; bf16x8 v; } ah, al;
                splitf(wa.x, ah.u[0], al.u[0]); splitf(wa.y, ah.u[1], al.u[1]);
                splitf(wa.z, ah.u[2], al.u[2]); splitf(wa.w, ah.u[3], al.u[3]);
                splitf(wb.x, ah.u[4], al.u[4]); splitf(wb.y, ah.u[5], al.u[5]);
                splitf(wb.z, ah.u[6], al.u[6]); splitf(wb.w, ah.u[7], al.u[7]);
                bf16x8 uh = *(const bf16x8*)(ub + m * 32);
                bf16x8 uo = *(const bf16x8*)(ul + m * 32);
                acc = __builtin_amdgcn_mfma_f32_16x16x32_bf16(ah.v, uh, acc, 0, 0, 0);
                acc = __builtin_amdgcn_mfma_f32_16x16x32_bf16(ah.v, uo, acc, 0, 0, 0);
                acc = __builtin_amdgcn_mfma_f32_16x16x32_bf16(al.v, uh, acc, 0, 0, 0);
            }
        }
        __builtin_amdgcn_sched_barrier(0);

        if (n > 0) {
            if (l == 0) {
                int it = 0;
                while (flag_load(&myflag[n - 1]) < NWG_DIR) {
                    if (++it > (1 << 14)) break;
                    __builtin_amdgcn_s_sleep(2);
                }
            }
            const unsigned short* hbh = hHi +
                ((size_t)((dir * 2 + ((n - 1) & 1)) * 16 + colb)) * 512 + khi * 8;
            const unsigned short* hbl = hLo +
                ((size_t)((dir * 2 + ((n - 1) & 1)) * 16 + colb)) * 512 + khi * 8;
            bf16x8 hh[16], hl[16];
#pragma unroll
            for (int m = 0; m < 16; ++m) {
                asm volatile("global_load_dwordx4 %0, %1, off sc0 sc1"
                             : "=v"(hh[m]) : "v"(hbh + m * 32));
                asm volatile("global_load_dwordx4 %0, %1, off sc0 sc1"
                             : "=v"(hl[m]) : "v"(hbl + m * 32));
            }
            asm volatile("s_waitcnt vmcnt(0)" ::: "memory");
            __builtin_amdgcn_sched_barrier(0);
            f32x4 accH = {0.f, 0.f, 0.f, 0.f};
#pragma unroll
            for (int m = 0; m < 16; ++m) {
                bf16x8 wh = *(const bf16x8*)&HHhi[(wv * 16 + colb) * PADsh + m * 32 + khi * 8];
                bf16x8 wl = *(const bf16x8*)&HHlo[(wv * 16 + colb) * PADsh + m * 32 + khi * 8];
                accH = __builtin_amdgcn_mfma_f32_16x16x32_bf16(wh, hh[m], accH, 0, 0, 0);
                accH = __builtin_amdgcn_mfma_f32_16x16x32_bf16(wh, hl[m], accH, 0, 0, 0);
                accH = __builtin_amdgcn_mfma_f32_16x16x32_bf16(wl, hh[m], accH, 0, 0, 0);
            }
            acc = acc + accH;
        }

        // ---- exchange gate tiles (waves f,g,o -> LDS) ----
        if (wv != 0) {
#pragma unroll
            for (int j = 0; j < 4; ++j)
                xch[(wv - 1) * 256 + (khi * 4 + j) * 16 + colb] = acc[j];
        }
        __syncthreads();

        // ---- wave 0: LSTM cell + split-h store + us-partial + flag ----
        if (wv == 0) {
            unsigned short hhi4[4], hlo4[4];
            float p = 0.f;
#pragma unroll
            for (int j = 0; j < 4; ++j) {
                int rr = khi * 4 + j;
                float gi = acc[j];
                float gf = xch[0 * 256 + rr * 16 + colb];
                float gg = xch[1 * 256 + rr * 16 + colb];
                float go = xch[2 * 256 + rr * 16 + colb];
                float c2 = sigm(gf) * cst[j] + sigm(gi) * tanhf(gg);
                cst[j] = c2;
                float h = sigm(go) * tanhf(c2);
                splitf(h, hhi4[j], hlo4[j]);
                p += h * w2v[j];
            }
            u64 qhi = (u64)hhi4[0] | ((u64)hhi4[1] << 16) | ((u64)hhi4[2] << 32) | ((u64)hhi4[3] << 48);
            u64 qlo = (u64)hlo4[0] | ((u64)hlo4[1] << 16) | ((u64)hlo4[2] << 32) | ((u64)hlo4[3] << 48);
            size_t hoff = ((size_t)((dir * 2 + (n & 1)) * 16 + colb)) * 512 + d0 + khi * 4;
            asm volatile("global_store_dwordx2 %0, %1, off sc0 sc1"
                         :: "v"(hHi + hoff), "v"(qhi) : "memory");
            asm volatile("global_store_dwordx2 %0, %1, off sc0 sc1"
                         :: "v"(hLo + hoff), "v"(qlo) : "memory");
            p += __shfl_xor(p, 16);
            p += __shfl_xor(p, 32);
            if (l < 16)
                part[((size_t)((dir * 32 + slice) * 16) + l) * TU + t] = p;
            asm volatile("s_waitcnt vmcnt(0)" ::: "memory");
            if (l == 0)
                atomicAdd(&myflag[n], 1);
        }
    }
}

// ---------------- K6: reduce us partials, activation, pre-norm ----------------
__global__ void k_us_reduce(const float* __restrict__ part, const float* __restrict__ ob2,
                            const float* __restrict__ mask, float* __restrict__ usA,
                            float* __restrict__ csum) {
    int b = blockIdx.x, ch = blockIdx.y;
    int t = ch * 256 + threadIdx.x;
    float s = 0.f;
#pragma unroll 8
    for (int p = 0; p < 64; ++p) s += part[((size_t)p * Bz + b) * TU + t];
    float u = sigm(s + ob2[0]);
    float ua = fmaxf(u * SM2c - NT2c, 0.f) * mask[b * Sz + t / 3];
    usA[b * TU + t] = ua;
    __shared__ float red[256];
    red[threadIdx.x] = ua;
    __syncthreads();
    for (int off = 128; off >= 1; off >>= 1) {
        if (threadIdx.x < off) red[threadIdx.x] += red[threadIdx.x + off];
        __syncthreads();
    }
    if (threadIdx.x == 0) csum[b * 6 + ch] = red[0];
}

// ---------------- K7: normalize + peak scan (serial per batch) ----------------
__global__ void k_us_scan(const float* __restrict__ usA, const float* __restrict__ csum,
                          float* __restrict__ out) {
    __shared__ float ubuf[TU];
    int b = blockIdx.x;
    for (int t = threadIdx.x; t < TU; t += 64) ubuf[t] = usA[b * TU + t];
    __syncthreads();
    if (threadIdx.x == 0) {
        float tot = 0.f;
        for (int c = 0; c < 6; ++c) tot += csum[b * 6 + c];
        float scale = out[TOK_OFF + b] / tot;
        float integ = 0.f;
        const float th = THRESHc - 0.0001f;
        for (int t = 0; t < TU; ++t) {
            float ua = ubuf[t] * scale;
            out[USA_OFF + b * TU + t] = ua;
            integ += ua;
            out[USP_OFF + b * TU + t] = integ;
            if (integ >= th) integ -= th;
        }
    }
}

// ---------------- host ----------------
extern "C" void kernel_launch(void* const* d_in, const int* in_sizes, int n_in,
                              void* d_out, int out_size, void* d_ws, size_t ws_size,
                              hipStream_t stream) {
    const float* hidden = (const float*)d_in[0];
    const float* mask   = (const float*)d_in[1];
    const float* conv_w = (const float*)d_in[2];
    const float* conv_b = (const float*)d_in[3];
    const float* out_w  = (const float*)d_in[4];
    const float* out_b  = (const float*)d_in[5];
    const float* up_w   = (const float*)d_in[6];
    const float* up_b   = (const float*)d_in[7];
    const float* w_ih_f = (const float*)d_in[8];
    const float* w_hh_f = (const float*)d_in[9];
    const float* b_ih_f = (const float*)d_in[10];
    const float* b_hh_f = (const float*)d_in[11];
    const float* w_ih_b = (const float*)d_in[12];
    const float* w_hh_b = (const float*)d_in[13];
    const float* b_ih_b = (const float*)d_in[14];
    const float* b_hh_b = (const float*)d_in[15];
    const float* out2_w = (const float*)d_in[16];
    const float* out2_b = (const float*)d_in[17];
    float* out = (float*)d_out;
    float* ws = (float*)d_ws;

    // workspace layout (float slots), total 14,253,200 floats = 57.0 MB (r1-proven size)
    float* wt     = ws + 0;              // 786,432 (dead after k_conv_alpha)
    float* part   = ws + 0;              // 1,572,864 (written by k_lstm, after conv)
    float* gconst = ws + 1572864;        // 4096
    float* alph_s = ws + 1576960;        // 8192
    float* sc_cur = ws + 1585152;        // 8208
    float* sc_res = ws + 1593360;        // 8208
    int*   sc_dst = (int*)(ws + 1601568);            // 8208
    unsigned short* hHi = (unsigned short*)(ws + 1609776);   // 32768 shorts
    unsigned short* hLo = (unsigned short*)(ws + 1626160);   // 32768 shorts
    float* usA    = ws + 1642544;        // 24576
    float* csum   = ws + 1667120;        // 96
    int*   flags  = (int*)(ws + 1667216);            // 2*1536 ints
    unsigned short* Uhi = (unsigned short*)(ws + 1670288);   // 12,582,912 shorts
    unsigned short* Ulo = (unsigned short*)(ws + 7961744);   // 12,582,912 shorts

    hipMemsetAsync(out, 0, (size_t)Bz * T1 * Dz * sizeof(float), stream);   // embeds region
    hipMemsetAsync(flags, 0, 2 * TU * sizeof(int), stream);

    k_transpose_convw<<<dim3(8, 24), 256, 0, stream>>>(conv_w, wt);
    k_gconst<<<16, 256, 0, stream>>>(w_ih_f, b_ih_f, b_hh_f, w_ih_b, b_ih_b, b_hh_b, up_b, gconst);
    k_U<<<dim3(8, 128, 3), 256, 0, stream>>>(hidden, up_w, Uhi, Ulo);
    k_conv_alpha<<<dim3(16, 32), 256, 0, stream>>>(hidden, wt, conv_b, out_w, out_b, mask, alph_s);
    k_cif_scan<<<1, 256, 0, stream>>>(alph_s, mask, out, sc_cur, sc_res, sc_dst);
    k_cif_frames<<<dim3(16, 2), 256, 0, stream>>>(hidden, sc_cur, sc_res, sc_dst, out);

    {
        size_t shmem = (size_t)(2 * 64 * PADsh) * sizeof(unsigned short)
                     + 3 * 256 * sizeof(float);   // 136,192 B
        hipFuncSetAttribute(reinterpret_cast<const void*>(&k_lstm),
                            hipFuncAttributeMaxDynamicSharedMemorySize, (int)(shmem + 1024));
        void* args[] = { (void*)&w_ih_f, (void*)&w_hh_f, (void*)&w_ih_b, (void*)&w_hh_b,
                         (void*)&gconst, (void*)&out2_w, (void*)&Uhi, (void*)&Ulo,
                         (void*)&hHi, (void*)&hLo, (void*)&part, (void*)&flags };
        hipLaunchCooperativeKernel(reinterpret_cast<void*>(&k_lstm), dim3(64), dim3(256),
                                   args, (unsigned)shmem, stream);
    }

    k_us_reduce<<<dim3(16, 6), 256, 0, stream>>>(part, out2_b, mask, usA, csum);
    k_us_scan<<<16, 64, 0, stream>>>(usA, csum, out);
}